// Round 1
// baseline (377.344 us; speedup 1.0000x reference)
//
#include <hip/hip_runtime.h>
#include <hip/hip_bf16.h>

#define D 256
#define TEMP_INV 20.0f   // 1 / 0.05

typedef __attribute__((ext_vector_type(8))) short bf16x8s;  // 8 bf16 in 4 VGPRs
typedef __attribute__((ext_vector_type(4))) float f32x4;

// ---- helpers ----------------------------------------------------------------
__device__ __forceinline__ unsigned short f2bf(float f) {
  // round-to-nearest-even float -> bf16 (inputs are finite)
  unsigned u = __float_as_uint(f);
  unsigned r = u + 0x7FFFu + ((u >> 16) & 1u);
  return (unsigned short)(r >> 16);
}
__device__ __forceinline__ float bf2f(unsigned short h) {
  return __uint_as_float(((unsigned)h) << 16);
}

// ---- kernel 1: row L2-normalize f32 -> bf16 ---------------------------------
// one wave per row (D=256 -> 4 f32 per lane)
__global__ __launch_bounds__(256) void nce_normalize(const float* __restrict__ src,
                                                     unsigned short* __restrict__ dst,
                                                     int nrows) {
  int row  = blockIdx.x * 4 + (threadIdx.x >> 6);
  int lane = threadIdx.x & 63;
  if (row >= nrows) return;
  float4 v = reinterpret_cast<const float4*>(src)[(size_t)row * (D / 4) + lane];
  float ss = v.x * v.x + v.y * v.y + v.z * v.z + v.w * v.w;
#pragma unroll
  for (int m = 1; m < 64; m <<= 1) ss += __shfl_xor(ss, m, 64);
  float inv = 1.0f / fmaxf(sqrtf(ss), 1e-12f);
  ushort4 o;
  o.x = f2bf(v.x * inv);
  o.y = f2bf(v.y * inv);
  o.z = f2bf(v.z * inv);
  o.w = f2bf(v.w * inv);
  reinterpret_cast<ushort4*>(dst)[(size_t)row * (D / 4) + lane] = o;
}

// ---- kernel 2: scores GEMM + per-row sum(exp(score)) ------------------------
// C[i,j] = A_n[i,:] . T_n[j,:]  (both row-major, K contiguous -> A and B
// fragments are 8 contiguous bf16 at row (lane&15), k-offset (lane>>4)*8).
// 128x128 block tile, 4 waves as 2x2, each wave 64x64 via 4x4 16x16x32 MFMAs.
__global__ __launch_bounds__(256) void nce_scores(const unsigned short* __restrict__ A,
                                                  const unsigned short* __restrict__ T,
                                                  float* __restrict__ rowsum) {
  const int lane = threadIdx.x & 63;
  const int wid  = threadIdx.x >> 6;
  const int wr = wid >> 1, wc = wid & 1;
  const int row0 = blockIdx.y * 128 + wr * 64;
  const int col0 = blockIdx.x * 128 + wc * 64;
  const int r = lane & 15, g = lane >> 4;

  const unsigned short* aBase = A + (size_t)(row0 + r) * D + g * 8;
  const unsigned short* tBase = T + (size_t)(col0 + r) * D + g * 8;

  f32x4 acc[4][4];
#pragma unroll
  for (int m = 0; m < 4; ++m)
#pragma unroll
    for (int n = 0; n < 4; ++n) acc[m][n] = (f32x4)0.0f;

#pragma unroll
  for (int kk = 0; kk < 8; ++kk) {          // K = 256 in steps of 32
    bf16x8s a[4], b[4];
#pragma unroll
    for (int m = 0; m < 4; ++m)
      a[m] = *reinterpret_cast<const bf16x8s*>(aBase + (size_t)m * 16 * D + kk * 32);
#pragma unroll
    for (int n = 0; n < 4; ++n)
      b[n] = *reinterpret_cast<const bf16x8s*>(tBase + (size_t)n * 16 * D + kk * 32);
#pragma unroll
    for (int m = 0; m < 4; ++m)
#pragma unroll
      for (int n = 0; n < 4; ++n)
        acc[m][n] = __builtin_amdgcn_mfma_f32_16x16x32_bf16(a[m], b[n], acc[m][n], 0, 0, 0);
  }

  // epilogue: scores bounded by |dot|<=1 -> score in [-20,20]; exp() safe in f32.
  // C/D layout: col = lane&15, row = (lane>>4)*4 + reg  [measured m89]
#pragma unroll
  for (int m = 0; m < 4; ++m) {
#pragma unroll
    for (int reg = 0; reg < 4; ++reg) {
      float s = 0.0f;
#pragma unroll
      for (int n = 0; n < 4; ++n) s += __expf(acc[m][n][reg] * TEMP_INV);
      // reduce across the 16 lanes that share this output row
      s += __shfl_xor(s, 1, 64);
      s += __shfl_xor(s, 2, 64);
      s += __shfl_xor(s, 4, 64);
      s += __shfl_xor(s, 8, 64);
      if (r == 0) atomicAdd(&rowsum[row0 + m * 16 + g * 4 + reg], s);
    }
  }
}

// ---- kernel 3: per-row loss = log(rowsum) - diag_score ----------------------
__global__ __launch_bounds__(256) void nce_rowloss(const unsigned short* __restrict__ A,
                                                   const unsigned short* __restrict__ T,
                                                   const float* __restrict__ rowsum,
                                                   float* __restrict__ rowloss,
                                                   int nrows) {
  int row  = blockIdx.x * 4 + (threadIdx.x >> 6);
  int lane = threadIdx.x & 63;
  if (row >= nrows) return;
  ushort4 av = reinterpret_cast<const ushort4*>(A)[(size_t)row * (D / 4) + lane];
  ushort4 tv = reinterpret_cast<const ushort4*>(T)[(size_t)row * (D / 4) + lane];
  float dot = bf2f(av.x) * bf2f(tv.x) + bf2f(av.y) * bf2f(tv.y) +
              bf2f(av.z) * bf2f(tv.z) + bf2f(av.w) * bf2f(tv.w);
#pragma unroll
  for (int m = 1; m < 64; m <<= 1) dot += __shfl_xor(dot, m, 64);
  if (lane == 0) rowloss[row] = logf(rowsum[row]) - dot * TEMP_INV;
}

// ---- kernel 4: mean over rows -> scalar -------------------------------------
__global__ __launch_bounds__(256) void nce_final(const float* __restrict__ rowloss,
                                                 float* __restrict__ out, int n) {
  __shared__ float red[4];
  float s = 0.0f;
  for (int i = threadIdx.x; i < n; i += 256) s += rowloss[i];
#pragma unroll
  for (int m = 1; m < 64; m <<= 1) s += __shfl_xor(s, m, 64);
  if ((threadIdx.x & 63) == 0) red[threadIdx.x >> 6] = s;
  __syncthreads();
  if (threadIdx.x == 0) out[0] = (red[0] + red[1] + red[2] + red[3]) / (float)n;
}

// ---- launch -----------------------------------------------------------------
extern "C" void kernel_launch(void* const* d_in, const int* in_sizes, int n_in,
                              void* d_out, int out_size, void* d_ws, size_t ws_size,
                              hipStream_t stream) {
  const float* anc = (const float*)d_in[0];
  const float* pos = (const float*)d_in[1];
  const float* neg = (const float*)d_in[2];
  const int B  = in_sizes[0] / D;   // 8192
  const int N2 = 2 * B;             // 16384

  char* ws = (char*)d_ws;
  unsigned short* An = (unsigned short*)ws;                          // B*D bf16
  unsigned short* Tn = (unsigned short*)(ws + (size_t)B * D * 2);    // 2B*D bf16
  float* rowsum  = (float*)(ws + (size_t)B * D * 2 + (size_t)N2 * D * 2);
  float* rowloss = rowsum + B;

  hipMemsetAsync(rowsum, 0, (size_t)B * sizeof(float), stream);

  nce_normalize<<<B / 4, 256, 0, stream>>>(anc, An, B);
  nce_normalize<<<B / 4, 256, 0, stream>>>(pos, Tn, B);
  nce_normalize<<<B / 4, 256, 0, stream>>>(neg, Tn + (size_t)B * D, B);

  dim3 grid(N2 / 128, B / 128);
  nce_scores<<<grid, 256, 0, stream>>>(An, Tn, rowsum);

  nce_rowloss<<<B / 4, 256, 0, stream>>>(An, Tn, rowsum, rowloss, B);
  nce_final<<<1, 256, 0, stream>>>(rowloss, (float*)d_out, B);
}

// Round 3
// 192.198 us; speedup vs baseline: 1.9633x; 1.9633x over previous
//
#include <hip/hip_runtime.h>
#include <hip/hip_bf16.h>

#define D 256
#define TEMP_INV 20.0f   // 1 / 0.05

typedef __attribute__((ext_vector_type(8))) short bf16x8s;  // 8 bf16 in 4 VGPRs
typedef __attribute__((ext_vector_type(4))) float f32x4;

// ---- helpers ----------------------------------------------------------------
__device__ __forceinline__ unsigned short f2bf(float f) {
  unsigned u = __float_as_uint(f);
  unsigned r = u + 0x7FFFu + ((u >> 16) & 1u);
  return (unsigned short)(r >> 16);
}

__device__ __forceinline__ void gld16(const void* g, void* l) {
  // async global->LDS, 16B/lane; LDS dest is wave-uniform base + lane*16
  __builtin_amdgcn_global_load_lds(
      (const __attribute__((address_space(1))) void*)g,
      (__attribute__((address_space(3))) void*)l, 16, 0, 0);
}

// ---- kernel 1: fused row L2-normalize f32 -> bf16 for all 3 inputs ----------
__global__ __launch_bounds__(256) void nce_normalize(const float* __restrict__ anc,
                                                     const float* __restrict__ pos,
                                                     const float* __restrict__ neg,
                                                     unsigned short* __restrict__ An,
                                                     unsigned short* __restrict__ Tn,
                                                     int B) {
  int row  = blockIdx.x * 4 + (threadIdx.x >> 6);
  int lane = threadIdx.x & 63;
  const float* src;
  unsigned short* dst;
  int r2;
  if (row < B)          { src = anc; dst = An; r2 = row; }
  else if (row < 2 * B) { src = pos; dst = Tn; r2 = row - B; }
  else                  { src = neg; dst = Tn + (size_t)B * D; r2 = row - 2 * B; }
  float4 v = reinterpret_cast<const float4*>(src)[(size_t)r2 * (D / 4) + lane];
  float ss = v.x * v.x + v.y * v.y + v.z * v.z + v.w * v.w;
#pragma unroll
  for (int m = 1; m < 64; m <<= 1) ss += __shfl_xor(ss, m, 64);
  float inv = 1.0f / fmaxf(sqrtf(ss), 1e-12f);
  ushort4 o;
  o.x = f2bf(v.x * inv);
  o.y = f2bf(v.y * inv);
  o.z = f2bf(v.z * inv);
  o.w = f2bf(v.w * inv);
  reinterpret_cast<ushort4*>(dst)[(size_t)r2 * (D / 4) + lane] = o;
}

// ---- kernel 2: MFMA GEMM (m97 structure) + sum(exp) + diag extraction -------
// 128x128 tile, BK=32, 4 waves (2x2), each wave 64x64 via 4x4 16x16x32 MFMAs.
// LDS per buffer: A 8KB + B 8KB, double-buffered (32KB). Staged with
// global_load_lds (lane-linear dest); bank-conflict-free ds_read_b128 via
// XOR swizzle implemented on BOTH sides: pre-swizzled global source address
// (stage) + swizzled byte offset (read).  [rule #21]
// Swizzle: rows are 64B (BK=32 bf16); superrow S = R>>1 (128B = 8 x 16B
// chunks); chunk p = (R&1)*4 + C stored at p' = p ^ (S&7).
__global__ __launch_bounds__(256) void nce_scores(const unsigned short* __restrict__ A,
                                                  const unsigned short* __restrict__ T,
                                                  float* __restrict__ rowsum,
                                                  float* __restrict__ diag) {
  __shared__ unsigned char smem[2][16384];   // [buf][A 8KB | B 8KB]
  __shared__ float rsum_lds[128];

  const int tid  = threadIdx.x;
  const int lane = tid & 63;
  const int wid  = __builtin_amdgcn_readfirstlane(tid >> 6);
  const int wr = wid >> 1, wc = wid & 1;
  const int row0 = blockIdx.y * 128;
  const int col0 = blockIdx.x * 128;

  // ---- staging: lane -> (R, C) via inverse swizzle ----
  // gload_lds writes lane i at slotbase*1024 + i*16 => S = slotbase*8 + (i>>3),
  // p' = i&7.  p = p' ^ (S&7) = (i&7) ^ (i>>3);  R = 2S + (p>>2);  C = p&3.
  const int pp    = (lane & 7) ^ (lane >> 3);
  const int Rbase = 2 * (lane >> 3) + (pp >> 2);   // + slot*16 (+ wid*32)
  const int Cb    = pp & 3;
  // global row stride = 512B (D=256 bf16); k-tile kt adds kt*64B; chunk C adds C*16
  const unsigned char* gA =
      (const unsigned char*)A + (((size_t)(row0 + wid * 32 + Rbase)) << 9) + Cb * 16;
  const unsigned char* gB =
      (const unsigned char*)T + (((size_t)(col0 + wid * 32 + Rbase)) << 9) + Cb * 16;

  // ---- fragment read offsets (swizzled) ----
  const int r = lane & 15, g = lane >> 4;
  const int S7   = (r >> 1) & 7;                       // (S&7) — wr*32,m*8 drop out
  const int pA   = (((r & 1) << 2) + g) ^ S7;
  const int offF = ((r >> 1) << 7) + (pA << 4);        // within region; +m*1024
  const int offA = wr * 4096 + offF;
  const int offB = 8192 + wc * 4096 + offF;

  auto STAGE = [&](int buf, int kt) {
    unsigned char* s = &smem[buf][0];
    const unsigned char* ga = gA + kt * 64;
    const unsigned char* gb = gB + kt * 64;
    gld16(ga,        s + wid * 2048);           // A slot 0 (16 rows)
    gld16(ga + 8192, s + wid * 2048 + 1024);    // A slot 1 (+16 rows = +8192B)
    gld16(gb,        s + 8192 + wid * 2048);    // B slot 0
    gld16(gb + 8192, s + 8192 + wid * 2048 + 1024);
  };

  f32x4 acc[4][4];
#pragma unroll
  for (int m = 0; m < 4; ++m)
#pragma unroll
    for (int n = 0; n < 4; ++n) acc[m][n] = (f32x4)0.0f;

  STAGE(0, 0);
  if (tid < 128) rsum_lds[tid] = 0.0f;
  __syncthreads();

#pragma unroll
  for (int kt = 0; kt < 8; ++kt) {             // K = 256, BK = 32
    const int cur = kt & 1;
    if (kt < 7) STAGE(cur ^ 1, kt + 1);        // prefetch next K-tile
    const unsigned char* sb = &smem[cur][0];
    bf16x8s af[4], bf_[4];
#pragma unroll
    for (int m = 0; m < 4; ++m) af[m]  = *(const bf16x8s*)(sb + offA + m * 1024);
#pragma unroll
    for (int n = 0; n < 4; ++n) bf_[n] = *(const bf16x8s*)(sb + offB + n * 1024);
#pragma unroll
    for (int m = 0; m < 4; ++m)
#pragma unroll
      for (int n = 0; n < 4; ++n)
        acc[m][n] = __builtin_amdgcn_mfma_f32_16x16x32_bf16(af[m], bf_[n], acc[m][n], 0, 0, 0);
    __syncthreads();                            // drains stage vmcnt + ds reads
  }

  // ---- epilogue: scores in [-20,20] -> exp safe in f32 ----
  // C/D layout: col = lane&15 (=r), row = g*4 + reg  [measured m89]
  const bool diagBlock = (row0 == col0);
#pragma unroll
  for (int m = 0; m < 4; ++m) {
#pragma unroll
    for (int reg = 0; reg < 4; ++reg) {
      float s = 0.0f;
#pragma unroll
      for (int n = 0; n < 4; ++n) s += __expf(acc[m][n][reg] * TEMP_INV);
      s += __shfl_xor(s, 1, 64);
      s += __shfl_xor(s, 2, 64);
      s += __shfl_xor(s, 4, 64);
      s += __shfl_xor(s, 8, 64);
      if (r == 0) atomicAdd(&rsum_lds[wr * 64 + m * 16 + g * 4 + reg], s);
      // diagonal score s_ii (raw dot): row==col when wr==wc, n==m, r==g*4+reg
      if (diagBlock && wr == wc && r == g * 4 + reg)
        diag[row0 + wr * 64 + m * 16 + r] = acc[m][m][reg];
    }
  }
  __syncthreads();
  if (tid < 128) atomicAdd(&rowsum[row0 + tid], rsum_lds[tid]);
}

// ---- kernel 3: loss_i = log(rowsum_i) - diag_i*20; mean -> scalar -----------
__global__ __launch_bounds__(1024) void nce_finalize(const float* __restrict__ rowsum,
                                                     const float* __restrict__ diag,
                                                     float* __restrict__ out, int n) {
  __shared__ float red[16];
  float s = 0.0f;
  for (int i = threadIdx.x; i < n; i += 1024)
    s += logf(rowsum[i]) - diag[i] * TEMP_INV;
#pragma unroll
  for (int m = 1; m < 64; m <<= 1) s += __shfl_xor(s, m, 64);
  if ((threadIdx.x & 63) == 0) red[threadIdx.x >> 6] = s;
  __syncthreads();
  if (threadIdx.x == 0) {
    float t = 0.0f;
#pragma unroll
    for (int i = 0; i < 16; ++i) t += red[i];
    out[0] = t / (float)n;
  }
}

// ---- launch -----------------------------------------------------------------
extern "C" void kernel_launch(void* const* d_in, const int* in_sizes, int n_in,
                              void* d_out, int out_size, void* d_ws, size_t ws_size,
                              hipStream_t stream) {
  const float* anc = (const float*)d_in[0];
  const float* pos = (const float*)d_in[1];
  const float* neg = (const float*)d_in[2];
  const int B  = in_sizes[0] / D;   // 8192
  const int N2 = 2 * B;             // 16384

  char* ws = (char*)d_ws;
  unsigned short* An = (unsigned short*)ws;                          // B*D bf16
  unsigned short* Tn = (unsigned short*)(ws + (size_t)B * D * 2);    // 2B*D bf16
  float* rowsum = (float*)(ws + (size_t)B * D * 2 + (size_t)N2 * D * 2);
  float* diag   = rowsum + B;

  hipMemsetAsync(rowsum, 0, (size_t)B * sizeof(float), stream);

  nce_normalize<<<3 * B / 4, 256, 0, stream>>>(anc, pos, neg, An, Tn, B);

  dim3 grid(N2 / 128, B / 128);
  nce_scores<<<grid, 256, 0, stream>>>(An, Tn, rowsum, diag);

  nce_finalize<<<1, 1024, 0, stream>>>(rowsum, diag, (float*)d_out, B);
}

// Round 4
// 148.796 us; speedup vs baseline: 2.5360x; 1.2917x over previous
//
#include <hip/hip_runtime.h>
#include <hip/hip_bf16.h>

#define D 256
#define TEMP_INV 20.0f   // 1 / 0.05
#define NJ 16            // 128-col tiles per colgroup (2048 cols per block)

typedef __attribute__((ext_vector_type(8))) short bf16x8s;  // 8 bf16 in 4 VGPRs
typedef __attribute__((ext_vector_type(4))) float f32x4;

// ---- helpers ----------------------------------------------------------------
__device__ __forceinline__ unsigned short f2bf(float f) {
  unsigned u = __float_as_uint(f);
  unsigned r = u + 0x7FFFu + ((u >> 16) & 1u);
  return (unsigned short)(r >> 16);
}

__device__ __forceinline__ void gld16(const void* g, void* l) {
  // async global->LDS, 16B/lane; LDS dest is wave-uniform base + lane*16
  __builtin_amdgcn_global_load_lds(
      (const __attribute__((address_space(1))) void*)g,
      (__attribute__((address_space(3))) void*)l, 16, 0, 0);
}

// ---- kernel 1: fused row L2-normalize f32 -> bf16 (3 inputs) + zero rowsum --
__global__ __launch_bounds__(256) void nce_normalize(const float* __restrict__ anc,
                                                     const float* __restrict__ pos,
                                                     const float* __restrict__ neg,
                                                     unsigned short* __restrict__ An,
                                                     unsigned short* __restrict__ Tn,
                                                     float* __restrict__ rowsum,
                                                     int B) {
  // first B/256 blocks also zero rowsum (stream-ordered before nce_scores)
  int zi = blockIdx.x * 256 + threadIdx.x;
  if (blockIdx.x < (B + 255) / 256 && zi < B) rowsum[zi] = 0.0f;

  int row  = blockIdx.x * 4 + (threadIdx.x >> 6);
  int lane = threadIdx.x & 63;
  const float* src;
  unsigned short* dst;
  int r2;
  if (row < B)          { src = anc; dst = An; r2 = row; }
  else if (row < 2 * B) { src = pos; dst = Tn; r2 = row - B; }
  else                  { src = neg; dst = Tn + (size_t)B * D; r2 = row - 2 * B; }
  float4 v = reinterpret_cast<const float4*>(src)[(size_t)r2 * (D / 4) + lane];
  float ss = v.x * v.x + v.y * v.y + v.z * v.z + v.w * v.w;
#pragma unroll
  for (int m = 1; m < 64; m <<= 1) ss += __shfl_xor(ss, m, 64);
  float inv = rsqrtf(fmaxf(ss, 1e-24f));   // ||x|| ~ 16 for N(0,1) rows; eps guard
  ushort4 o;
  o.x = f2bf(v.x * inv);
  o.y = f2bf(v.y * inv);
  o.z = f2bf(v.z * inv);
  o.w = f2bf(v.w * inv);
  reinterpret_cast<ushort4*>(dst)[(size_t)r2 * (D / 4) + lane] = o;
}

// ---- kernel 2: A-in-registers MFMA GEMM + sum(exp) + diag extraction --------
// Each block: 128 rows x 2048 cols, K=256. A panel (64 rows x 256 K per wave)
// lives entirely in VGPRs (32x bf16x8 = 128 VGPR). Only B streams through LDS
// (double-buffered 2x8KB), staged with global_load_lds w=16 and the validated
// XOR swizzle (pre-swizzled global source + swizzled read offsets, rule #21).
// 4 waves as 2x2; per K-step: 4 ds_read_b128 + 16 MFMA (4:1).
// Per-lane running sum(exp) regs across the 16 col-tiles; one reduce at end.
__global__ __launch_bounds__(256, 2) void nce_scores(const unsigned short* __restrict__ A,
                                                     const unsigned short* __restrict__ T,
                                                     float* __restrict__ rowsum,
                                                     float* __restrict__ diag) {
  __shared__ unsigned char smem[2][8192];   // B tile double buffer

  const int tid  = threadIdx.x;
  const int lane = tid & 63;
  const int wid  = __builtin_amdgcn_readfirstlane(tid >> 6);
  const int wr = wid >> 1, wc = wid & 1;
  const int row0 = blockIdx.y * 128;
  const int cg   = blockIdx.x;              // colgroup: cols [cg*2048, +2048)
  const int r = lane & 15, g = lane >> 4;

  // ---- B staging: lane -> (R, C) via inverse swizzle ----
  // gload_lds writes lane i at base + i*16 => superrow S = slot*8 + (i>>3),
  // p' = i&7;  p = p' ^ (S&7) = (i&7)^(i>>3);  R = 2S + (p>>2);  C = p&3.
  const int pp    = (lane & 7) ^ (lane >> 3);
  const int Rbase = 2 * (lane >> 3) + (pp >> 2);
  const int Cb    = pp & 3;
  // global row stride 512B; j adds j*128 rows (65536B); kt adds kt*64B
  const unsigned char* gB = (const unsigned char*)T +
      (((size_t)(cg * 2048 + wid * 32 + Rbase)) << 9) + Cb * 16;

  auto STAGE = [&](int buf, int s) {        // s = j*8 + kt
    const unsigned char* gb = gB + (size_t)(s >> 3) * 65536 + (s & 7) * 64;
    unsigned char* sb = &smem[buf][0];
    gld16(gb,        sb + wid * 2048);           // rows [wid*32, +16)
    gld16(gb + 8192, sb + wid * 2048 + 1024);    // rows [wid*32+16, +16)
  };

  // ---- fragment read offsets (swizzled), within 8KB buffer ----
  const int S7   = (r >> 1) & 7;
  const int pA   = (((r & 1) << 2) + g) ^ S7;
  const int offF = ((r >> 1) << 7) + (pA << 4);
  const int offB = wc * 4096 + offF;            // + n*1024 per fragment

  STAGE(0, 0);

  // ---- load the wave's whole A panel into registers (64 rows x 256 K) ----
  const unsigned short* aPtr = A + (size_t)(row0 + wr * 64 + r) * D + g * 8;
  bf16x8s aF[4][8];
#pragma unroll
  for (int m = 0; m < 4; ++m)
#pragma unroll
    for (int kt = 0; kt < 8; ++kt)
      aF[m][kt] = *reinterpret_cast<const bf16x8s*>(aPtr + (size_t)m * 16 * D + kt * 32);

  float rs[4][4];
#pragma unroll
  for (int m = 0; m < 4; ++m)
#pragma unroll
    for (int reg = 0; reg < 4; ++reg) rs[m][reg] = 0.0f;

  __syncthreads();

  for (int j = 0; j < NJ; ++j) {
    f32x4 acc[4][4];
#pragma unroll
    for (int m = 0; m < 4; ++m)
#pragma unroll
      for (int n = 0; n < 4; ++n) acc[m][n] = (f32x4)0.0f;

#pragma unroll
    for (int kt = 0; kt < 8; ++kt) {
      const int s = j * 8 + kt;
      if (s < NJ * 8 - 1) STAGE((s & 1) ^ 1, s + 1);   // prefetch next B slice
      const unsigned char* sb = &smem[s & 1][0];
      bf16x8s bF[4];
#pragma unroll
      for (int n = 0; n < 4; ++n)
        bF[n] = *reinterpret_cast<const bf16x8s*>(sb + offB + n * 1024);
#pragma unroll
      for (int m = 0; m < 4; ++m)
#pragma unroll
        for (int n = 0; n < 4; ++n)
          acc[m][n] = __builtin_amdgcn_mfma_f32_16x16x32_bf16(aF[m][kt], bF[n], acc[m][n], 0, 0, 0);
      __syncthreads();                                  // drains stage + ds reads
    }

    // ---- per-tile epilogue: scores in [-20,20]; accumulate exp in regs ----
    // C/D layout: col = lane&15 (=r), row = g*4 + reg  [measured m89]
    const bool diagTile = (cg * NJ + j == (int)blockIdx.y);
#pragma unroll
    for (int m = 0; m < 4; ++m) {
#pragma unroll
      for (int reg = 0; reg < 4; ++reg) {
        float s = 0.0f;
#pragma unroll
        for (int n = 0; n < 4; ++n) s += __expf(acc[m][n][reg] * TEMP_INV);
        rs[m][reg] += s;
        // diagonal raw score: row==col when wr==wc, n==m, r==g*4+reg
        if (diagTile && wr == wc && r == g * 4 + reg)
          diag[row0 + wr * 64 + m * 16 + r] = acc[m][m][reg];
      }
    }
  }

  // ---- once per block: reduce 16-lane groups, atomic into global rowsum ----
#pragma unroll
  for (int m = 0; m < 4; ++m) {
#pragma unroll
    for (int reg = 0; reg < 4; ++reg) {
      float s = rs[m][reg];
      s += __shfl_xor(s, 1, 64);
      s += __shfl_xor(s, 2, 64);
      s += __shfl_xor(s, 4, 64);
      s += __shfl_xor(s, 8, 64);
      if (r == 0) atomicAdd(&rowsum[row0 + wr * 64 + m * 16 + g * 4 + reg], s);
    }
  }
}

// ---- kernel 3: loss_i = log(rowsum_i) - diag_i*20; mean -> scalar -----------
__global__ __launch_bounds__(1024) void nce_finalize(const float* __restrict__ rowsum,
                                                     const float* __restrict__ diag,
                                                     float* __restrict__ out, int n) {
  __shared__ float red[16];
  float s = 0.0f;
  for (int i = threadIdx.x; i < n; i += 1024)
    s += logf(rowsum[i]) - diag[i] * TEMP_INV;
#pragma unroll
  for (int m = 1; m < 64; m <<= 1) s += __shfl_xor(s, m, 64);
  if ((threadIdx.x & 63) == 0) red[threadIdx.x >> 6] = s;
  __syncthreads();
  if (threadIdx.x == 0) {
    float t = 0.0f;
#pragma unroll
    for (int i = 0; i < 16; ++i) t += red[i];
    out[0] = t / (float)n;
  }
}

// ---- launch -----------------------------------------------------------------
extern "C" void kernel_launch(void* const* d_in, const int* in_sizes, int n_in,
                              void* d_out, int out_size, void* d_ws, size_t ws_size,
                              hipStream_t stream) {
  const float* anc = (const float*)d_in[0];
  const float* pos = (const float*)d_in[1];
  const float* neg = (const float*)d_in[2];
  const int B  = in_sizes[0] / D;   // 8192
  const int N2 = 2 * B;             // 16384

  char* ws = (char*)d_ws;
  unsigned short* An = (unsigned short*)ws;                          // B*D bf16
  unsigned short* Tn = (unsigned short*)(ws + (size_t)B * D * 2);    // 2B*D bf16
  float* rowsum = (float*)(ws + (size_t)B * D * 2 + (size_t)N2 * D * 2);
  float* diag   = rowsum + B;

  nce_normalize<<<3 * B / 4, 256, 0, stream>>>(anc, pos, neg, An, Tn, rowsum, B);

  dim3 grid(N2 / (NJ * 128), B / 128);   // (8, 64) = 512 blocks = 2/CU
  nce_scores<<<grid, 256, 0, stream>>>(An, Tn, rowsum, diag);

  nce_finalize<<<1, 1024, 0, stream>>>(rowsum, diag, (float*)d_out, B);
}

// Round 5
// 140.070 us; speedup vs baseline: 2.6940x; 1.0623x over previous
//
#include <hip/hip_runtime.h>
#include <hip/hip_bf16.h>

#define D 256
#define TEMP_INV 20.0f   // 1 / 0.05
#define NJ 16            // 128-col tiles per colgroup (2048 cols per block)
#define NS (NJ * 8)      // K-steps per block (BK=32, K=256 -> 8 per j-tile)

typedef __attribute__((ext_vector_type(8))) short bf16x8s;  // 8 bf16 in 4 VGPRs
typedef __attribute__((ext_vector_type(4))) float f32x4;

// ---- helpers ----------------------------------------------------------------
__device__ __forceinline__ unsigned short f2bf(float f) {
  unsigned u = __float_as_uint(f);
  unsigned r = u + 0x7FFFu + ((u >> 16) & 1u);
  return (unsigned short)(r >> 16);
}

__device__ __forceinline__ void gld16(const void* g, void* l) {
  // async global->LDS, 16B/lane; LDS dest is wave-uniform base + lane*16
  __builtin_amdgcn_global_load_lds(
      (const __attribute__((address_space(1))) void*)g,
      (__attribute__((address_space(3))) void*)l, 16, 0, 0);
}

// ---- kernel 1: fused row L2-normalize f32 -> bf16 (3 inputs) + zero rowsum --
// 16 lanes per row, 4 rows per wave, 16 rows per block: 4 independent float4
// loads per lane (MLP) + 4-step xor reduce (vs 1 load + 6-step chain before).
__global__ __launch_bounds__(256) void nce_normalize(const float* __restrict__ anc,
                                                     const float* __restrict__ pos,
                                                     const float* __restrict__ neg,
                                                     unsigned short* __restrict__ An,
                                                     unsigned short* __restrict__ Tn,
                                                     float* __restrict__ rowsum,
                                                     int B) {
  // first B/256 blocks also zero rowsum (stream-ordered before nce_scores)
  int zi = blockIdx.x * 256 + threadIdx.x;
  if (blockIdx.x < (B + 255) / 256 && zi < B) rowsum[zi] = 0.0f;

  const int lane = threadIdx.x & 63;
  const int wid  = threadIdx.x >> 6;
  const int sub  = lane >> 4, lr = lane & 15;
  int row = blockIdx.x * 16 + wid * 4 + sub;

  const float* src;
  unsigned short* dst;
  int r2;
  if (row < B)          { src = anc; dst = An; r2 = row; }
  else if (row < 2 * B) { src = pos; dst = Tn; r2 = row - B; }
  else                  { src = neg; dst = Tn + (size_t)B * D; r2 = row - 2 * B; }

  const float4* sp = reinterpret_cast<const float4*>(src) + (size_t)r2 * (D / 4);
  float4 v[4];
#pragma unroll
  for (int c = 0; c < 4; ++c) v[c] = sp[lr + c * 16];
  float ss = 0.0f;
#pragma unroll
  for (int c = 0; c < 4; ++c)
    ss += v[c].x * v[c].x + v[c].y * v[c].y + v[c].z * v[c].z + v[c].w * v[c].w;
  ss += __shfl_xor(ss, 1, 64);
  ss += __shfl_xor(ss, 2, 64);
  ss += __shfl_xor(ss, 4, 64);
  ss += __shfl_xor(ss, 8, 64);
  float inv = rsqrtf(fmaxf(ss, 1e-24f));
  ushort4* dp = reinterpret_cast<ushort4*>(dst) + (size_t)r2 * (D / 4);
#pragma unroll
  for (int c = 0; c < 4; ++c) {
    ushort4 o;
    o.x = f2bf(v[c].x * inv);
    o.y = f2bf(v[c].y * inv);
    o.z = f2bf(v[c].z * inv);
    o.w = f2bf(v[c].w * inv);
    dp[lr + c * 16] = o;
  }
}

// ---- kernel 2: A-in-registers MFMA GEMM, counted-vmcnt ring pipeline --------
// Each block: 128 rows x 2048 cols, K=256. A panel (64 rows x 256 K per wave)
// lives in VGPRs. B streams through a 4-buffer LDS ring (4x8KB), staged with
// global_load_lds w=16 + validated XOR swizzle (pre-swizzled global source +
// swizzled read offsets, rule #21). Prefetch depth 3; per step:
//   vmcnt(4) -> raw s_barrier -> ds_read b128 x4 -> STAGE(s+3)
//   -> lgkmcnt(0)+sched_barrier -> setprio(1) 16x MFMA setprio(0) -> sched_barrier
// Raw s_barrier (not __syncthreads) avoids the compiler's vmcnt(0) drain; the
// explicit lgkmcnt(0) before MFMA (pinned by sched_barrier) guarantees every
// wave's ds_reads of step s-1 are drained before anyone stages into that
// buffer at step s+? (ring distance 3 of 4).
__global__ __launch_bounds__(256, 2) void nce_scores(const unsigned short* __restrict__ A,
                                                     const unsigned short* __restrict__ T,
                                                     float* __restrict__ rowsum,
                                                     float* __restrict__ diag) {
  __shared__ unsigned char smem[4][8192];   // B tile ring buffer

  const int tid  = threadIdx.x;
  const int lane = tid & 63;
  const int wid  = __builtin_amdgcn_readfirstlane(tid >> 6);
  const int wr = wid >> 1, wc = wid & 1;
  const int row0 = blockIdx.y * 128;
  const int cg   = blockIdx.x;              // colgroup: cols [cg*2048, +2048)
  const int r = lane & 15, g = lane >> 4;

  // ---- B staging: lane -> (R, C) via inverse swizzle ----
  // gload_lds writes lane i at base + i*16 => superrow S = slot*8 + (i>>3),
  // p' = i&7;  p = p' ^ (S&7) = (i&7)^(i>>3);  R = 2S + (p>>2);  C = p&3.
  const int pp    = (lane & 7) ^ (lane >> 3);
  const int Rbase = 2 * (lane >> 3) + (pp >> 2);
  const int Cb    = pp & 3;
  // global row stride 512B; step s: j = s>>3 adds j*128 rows (65536B), kt = s&7 adds kt*64B
  const unsigned char* gB = (const unsigned char*)T +
      (((size_t)(cg * 2048 + wid * 32 + Rbase)) << 9) + Cb * 16;

  auto STAGE = [&](int s) {                 // dst buffer = s & 3
    const unsigned char* gb = gB + (size_t)(s >> 3) * 65536 + (s & 7) * 64;
    unsigned char* sb = &smem[s & 3][0];
    gld16(gb,        sb + wid * 2048);           // rows [wid*32, +16)
    gld16(gb + 8192, sb + wid * 2048 + 1024);    // rows [wid*32+16, +16)
  };

  // ---- fragment read offsets (swizzled), within one 8KB buffer ----
  const int S7   = (r >> 1) & 7;
  const int pA   = (((r & 1) << 2) + g) ^ S7;
  const int offF = ((r >> 1) << 7) + (pA << 4);
  const int offB = wc * 4096 + offF;            // + n*1024 per fragment

  // ---- load the wave's whole A panel into registers (64 rows x 256 K) ----
  const unsigned short* aPtr = A + (size_t)(row0 + wr * 64 + r) * D + g * 8;
  bf16x8s aF[4][8];
#pragma unroll
  for (int m = 0; m < 4; ++m)
#pragma unroll
    for (int kt = 0; kt < 8; ++kt)
      aF[m][kt] = *reinterpret_cast<const bf16x8s*>(aPtr + (size_t)m * 16 * D + kt * 32);

  // prefetch depth 3 (6 gload_lds in flight at steady state)
  STAGE(0);
  STAGE(1);
  STAGE(2);

  float rs[4][4];
#pragma unroll
  for (int m = 0; m < 4; ++m)
#pragma unroll
    for (int reg = 0; reg < 4; ++reg) rs[m][reg] = 0.0f;

  for (int j = 0; j < NJ; ++j) {
    f32x4 acc[4][4];
#pragma unroll
    for (int m = 0; m < 4; ++m)
#pragma unroll
      for (int n = 0; n < 4; ++n) acc[m][n] = (f32x4)0.0f;

#pragma unroll
    for (int kt = 0; kt < 8; ++kt) {
      const int s = j * 8 + kt;
      // stage s retired when <=4 vm ops outstanding (in-order retirement)
      asm volatile("s_waitcnt vmcnt(4)" ::: "memory");
      __builtin_amdgcn_s_barrier();
      const unsigned char* sb = &smem[s & 3][0];
      bf16x8s bF[4];
#pragma unroll
      for (int n = 0; n < 4; ++n)
        bF[n] = *reinterpret_cast<const bf16x8s*>(sb + offB + n * 1024);
      if (s + 3 < NS) STAGE(s + 3);
      asm volatile("s_waitcnt lgkmcnt(0)" ::: "memory");
      __builtin_amdgcn_sched_barrier(0);
      __builtin_amdgcn_s_setprio(1);
#pragma unroll
      for (int m = 0; m < 4; ++m)
#pragma unroll
        for (int n = 0; n < 4; ++n)
          acc[m][n] = __builtin_amdgcn_mfma_f32_16x16x32_bf16(aF[m][kt], bF[n], acc[m][n], 0, 0, 0);
      __builtin_amdgcn_s_setprio(0);
      __builtin_amdgcn_sched_barrier(0);
    }

    // ---- per-tile epilogue: scores in [-20,20]; accumulate exp in regs ----
    // C/D layout: col = lane&15 (=r), row = g*4 + reg  [measured m89]
    const bool diagTile = (cg * NJ + j == (int)blockIdx.y);
#pragma unroll
    for (int m = 0; m < 4; ++m) {
#pragma unroll
      for (int reg = 0; reg < 4; ++reg) {
        float s = 0.0f;
#pragma unroll
        for (int n = 0; n < 4; ++n) s += __expf(acc[m][n][reg] * TEMP_INV);
        rs[m][reg] += s;
        // diagonal raw score: row==col when wr==wc, n==m, r==g*4+reg
        if (diagTile && wr == wc && r == g * 4 + reg)
          diag[row0 + wr * 64 + m * 16 + r] = acc[m][m][reg];
      }
    }
  }

  // ---- once per block: reduce 16-lane groups, atomic into global rowsum ----
#pragma unroll
  for (int m = 0; m < 4; ++m) {
#pragma unroll
    for (int reg = 0; reg < 4; ++reg) {
      float s = rs[m][reg];
      s += __shfl_xor(s, 1, 64);
      s += __shfl_xor(s, 2, 64);
      s += __shfl_xor(s, 4, 64);
      s += __shfl_xor(s, 8, 64);
      if (r == 0) atomicAdd(&rowsum[row0 + wr * 64 + m * 16 + g * 4 + reg], s);
    }
  }
}

// ---- kernel 3: loss_i = log(rowsum_i) - diag_i*20; mean -> scalar -----------
__global__ __launch_bounds__(1024) void nce_finalize(const float* __restrict__ rowsum,
                                                     const float* __restrict__ diag,
                                                     float* __restrict__ out, int n) {
  __shared__ float red[16];
  float s = 0.0f;
  for (int i = threadIdx.x; i < n; i += 1024)
    s += logf(rowsum[i]) - diag[i] * TEMP_INV;
#pragma unroll
  for (int m = 1; m < 64; m <<= 1) s += __shfl_xor(s, m, 64);
  if ((threadIdx.x & 63) == 0) red[threadIdx.x >> 6] = s;
  __syncthreads();
  if (threadIdx.x == 0) {
    float t = 0.0f;
#pragma unroll
    for (int i = 0; i < 16; ++i) t += red[i];
    out[0] = t / (float)n;
  }
}

// ---- launch -----------------------------------------------------------------
extern "C" void kernel_launch(void* const* d_in, const int* in_sizes, int n_in,
                              void* d_out, int out_size, void* d_ws, size_t ws_size,
                              hipStream_t stream) {
  const float* anc = (const float*)d_in[0];
  const float* pos = (const float*)d_in[1];
  const float* neg = (const float*)d_in[2];
  const int B  = in_sizes[0] / D;   // 8192
  const int N2 = 2 * B;             // 16384

  char* ws = (char*)d_ws;
  unsigned short* An = (unsigned short*)ws;                          // B*D bf16
  unsigned short* Tn = (unsigned short*)(ws + (size_t)B * D * 2);    // 2B*D bf16
  float* rowsum = (float*)(ws + (size_t)B * D * 2 + (size_t)N2 * D * 2);
  float* diag   = rowsum + B;

  nce_normalize<<<3 * B / 16, 256, 0, stream>>>(anc, pos, neg, An, Tn, rowsum, B);

  dim3 grid(N2 / (NJ * 128), B / 128);   // (8, 64) = 512 blocks = 2/CU
  nce_scores<<<grid, 256, 0, stream>>>(An, Tn, rowsum, diag);

  nce_finalize<<<1, 1024, 0, stream>>>(rowsum, diag, (float*)d_out, B);
}